// Round 13
// baseline (298.374 us; speedup 1.0000x reference)
//
#include <hip/hip_runtime.h>

// WaveletParsingLayer: per-row stable stream compaction.
// x3[B,C,L] -> out[B,C,KEEP], dropping elements == FILLER (10.1f), order-preserving.
//
// R17 == R15 resubmitted (R15 and R16 both died on GPUAcquisitionTimeout
// before compile/run; no new evidence — resubmitting the ablation verbatim).
//
// R15: ABLATION ROUND. Five structures (R5 staged 79, R9 ILP 78, R12 ring 82,
// R13 two-pass ~100, R14 direct-store 86-89) all land 78-90us; convoy/ILP/
// concurrency/LDS-stage theories each falsified. R14 confound: compiler kept
// VGPR=40 and re-loaded the payload from L2 in phase B (FETCH/WRITE clean,
// L2 hits invisible) — the intended experiment never ran. Per m164/m165:
// stop hypothesizing, ablate. Probes run FIRST; the proven-correct R9 kernel
// runs LAST and writes every output element -> correctness unaffected.
//   Probe A: load+ballot only (no stores), x2 reps. Floor ~21us/rep.
//   Probe B: stores only (48 scalar stride-3 scattered stores/thread, the
//            real kernel's store pattern; j-outer to prevent dwordx3 merge),
//            x2 reps. Floor ~16us/rep.
// Pre-committed read: A high -> load path wall; B high -> scatter-store wall
// (in-register run packing next); both low -> dependency-chain wall (cross-
// row wave pipelining next); A+B~78 -> phases add (more blocks / overlap).

#define FILLER_VAL 10.1f
constexpr int L_LEN    = 16384;
constexpr int KEEP_LEN = 12288;
constexpr int WAVE     = 64;

// ======================= Probe A: load + ballot =======================
constexpr int A_BLOCK = 256;
constexpr int A_SEGS  = 4;
constexpr int A_SEG   = L_LEN / A_SEGS;      // 4096 elems per wave-segment
constexpr int A_CHUNK = WAVE * 4;            // 256
constexpr int A_CPS   = A_SEG / A_CHUNK;     // 16
constexpr int A_PF    = 8;

__global__ __launch_bounds__(A_BLOCK, 8) void probe_load_kernel(
    const float* __restrict__ x3, int* __restrict__ sink, int reps)
{
    const int row  = blockIdx.x;
    const int lane = threadIdx.x & 63;
    const int w    = threadIdx.x >> 6;
    const float* __restrict__ s = x3 + (size_t)row * L_LEN + w * A_SEG;

    int total = 0;
    #pragma unroll 1
    for (int rep = 0; rep < reps; ++rep) {
        #pragma unroll 1
        for (int h = 0; h < A_CPS / A_PF; ++h) {
            float4 buf[A_PF];
            #pragma unroll
            for (int i = 0; i < A_PF; ++i)
                buf[i] = *reinterpret_cast<const float4*>(
                    s + (h * A_PF + i) * A_CHUNK + lane * 4);
            #pragma unroll
            for (int i = 0; i < A_PF; ++i) {
                total += __popcll(__ballot(buf[i].x != FILLER_VAL))
                       + __popcll(__ballot(buf[i].y != FILLER_VAL))
                       + __popcll(__ballot(buf[i].z != FILLER_VAL))
                       + __popcll(__ballot(buf[i].w != FILLER_VAL));
            }
        }
    }
    if (lane == 0) sink[row * A_SEGS + w] = total;
}

// ======================= Probe B: scattered stores =======================
constexpr int B_BLOCK = 256;
constexpr int B_CHUNK = B_BLOCK * 4;         // 1024
constexpr int B_NC    = L_LEN / B_CHUNK;     // 16

__global__ __launch_bounds__(B_BLOCK, 8) void probe_store_kernel(
    float* __restrict__ out, int reps)
{
    const int row = blockIdx.x;
    float* __restrict__ o = out + (size_t)row * KEEP_LEN;
    const int tid = threadIdx.x;

    #pragma unroll 1
    for (int rep = 0; rep < reps; ++rep) {
        // j-outer: each store instruction has stride-3 lane addresses
        // (spans ~768B), matching the real kernel's dense-scatter character;
        // per-thread addresses across j differ by +1 but live in different
        // loops so the compiler can't fuse them into dwordx3.
        #pragma unroll
        for (int j = 0; j < 3; ++j) {
            #pragma unroll
            for (int c = 0; c < B_NC; ++c) {
                const int e = c * B_BLOCK + tid;          // 4-group index
                const int p = e * 3 + j;                  // dense scatter slot
                o[p] = (float)(e + j + rep);
            }
        }
    }
}

// ======================= Real kernel (R9, 78us, verified) =======================
constexpr int BLOCK = 256;           // 4 waves of 64
constexpr int NW    = BLOCK / 64;
constexpr int CHUNK = BLOCK * 4;     // 1024
constexpr int NC    = L_LEN / CHUNK; // 16
constexpr int RPB   = 2;             // rows per block

__global__ __launch_bounds__(BLOCK, 3) void compact_rows_kernel(
    const float* __restrict__ x3, float* __restrict__ out, int rows)
{
    const int tid  = threadIdx.x;
    const int lane = tid & 63;
    const int wid  = tid >> 6;
    const unsigned long long lt = (1ULL << lane) - 1ULL;

    __shared__ float stage[KEEP_LEN];   // 48 KB survivor value staging
    __shared__ int wtot[NC][NW];

    #pragma unroll
    for (int r = 0; r < RPB; ++r) {
        const int row = blockIdx.x * RPB + r;
        if (row >= rows) break;
        const float* __restrict__ in = x3 + (size_t)row * L_LEN;
        float* __restrict__ o = out + (size_t)row * KEEP_LEN;

        float4 v[NC];
        #pragma unroll
        for (int c = 0; c < NC; ++c)
            v[c] = *reinterpret_cast<const float4*>(in + c * CHUNK + tid * 4);

        int pk[NC];
        #pragma unroll
        for (int c = 0; c < NC; ++c) {
            const unsigned long long m0 = __ballot(v[c].x != FILLER_VAL);
            const unsigned long long m1 = __ballot(v[c].y != FILLER_VAL);
            const unsigned long long m2 = __ballot(v[c].z != FILLER_VAL);
            const unsigned long long m3 = __ballot(v[c].w != FILLER_VAL);
            const int before = __popcll(m0 & lt) + __popcll(m1 & lt)
                             + __popcll(m2 & lt) + __popcll(m3 & lt);
            const int bits = (int)((m0 >> lane) & 1ULL)
                           | ((int)((m1 >> lane) & 1ULL) << 1)
                           | ((int)((m2 >> lane) & 1ULL) << 2)
                           | ((int)((m3 >> lane) & 1ULL) << 3);
            pk[c] = bits | (before << 4);
            if (lane == 0)
                wtot[c][wid] = __popcll(m0) + __popcll(m1)
                             + __popcll(m2) + __popcll(m3);
        }
        __syncthreads();   // wtot visible; also protects stage reuse (r>0)

        int run = 0;
        #pragma unroll
        for (int c = 0; c < NC; ++c) {
            int wb = run;
            #pragma unroll
            for (int w = 0; w < NW; ++w) {
                const int t = wtot[c][w];
                if (w < wid) wb += t;
                run += t;
            }
            const int bits   = pk[c] & 15;
            const int before = pk[c] >> 4;
            const int p0 = wb + before;
            const int p1 = p0 + (bits & 1);
            const int p2 = p1 + ((bits >> 1) & 1);
            const int p3 = p2 + ((bits >> 2) & 1);
            if ((bits & 1) && p0 < KEEP_LEN) stage[p0] = v[c].x;
            if ((bits & 2) && p1 < KEEP_LEN) stage[p1] = v[c].y;
            if ((bits & 4) && p2 < KEEP_LEN) stage[p2] = v[c].z;
            if ((bits & 8) && p3 < KEEP_LEN) stage[p3] = v[c].w;
        }
        __syncthreads();   // stage complete

        #pragma unroll
        for (int k = 0; k < KEEP_LEN / (BLOCK * 4); ++k) {
            const int idx = (k * BLOCK + tid) * 4;
            *reinterpret_cast<float4*>(&o[idx]) =
                *reinterpret_cast<const float4*>(&stage[idx]);
        }
    }
}

extern "C" void kernel_launch(void* const* d_in, const int* in_sizes, int n_in,
                              void* d_out, int out_size, void* d_ws, size_t ws_size,
                              hipStream_t stream)
{
    // in order: x1 [B,C,4096] f32 (unused), x2 [B,C,4096] f32 (unused),
    //           x3 [B,C,L] f32, keep_len (scalar int, value 12288)
    const float* x3 = (const float*)d_in[2];
    float* out = (float*)d_out;
    int* sink = (int*)d_ws;                // 32 KB of workspace

    const int rows = in_sizes[2] / L_LEN;  // B*C = 2048

    // Probes first (outputs overwritten by the real kernel afterwards).
    probe_load_kernel<<<rows, A_BLOCK, 0, stream>>>(x3, sink, 2);
    probe_store_kernel<<<rows, B_BLOCK, 0, stream>>>(out, 2);

    // Real kernel last: writes every output element (correctness).
    compact_rows_kernel<<<(rows + RPB - 1) / RPB, BLOCK, 0, stream>>>(x3, out, rows);
}

// Round 15
// 260.633 us; speedup vs baseline: 1.1448x; 1.1448x over previous
//
#include <hip/hip_runtime.h>

// WaveletParsingLayer: per-row stable stream compaction.
// x3[B,C,L] -> out[B,C,KEEP], dropping elements == FILLER (10.1f), order-preserving.
//
// R19 == R18 resubmitted (R18 died on GPUAcquisitionTimeout; never ran).
//
// R18: ablation (R17) resolved: probe A (loads+ballots, 268MB) < 78us total
// and probe B (scattered scalar stores, 202MB) < 78us total -> NEITHER path
// is the wall; real kernel = 78 ~= 2x the sum of phase floors. Last
// unisolated variable: residency (probes 8 blocks/CU vs staged kernels'
// 3 blocks/CU from 48KB LDS; identical blocks phase-lock, 3 streams can't
// fill the pipes). Fix: HALF-ROW blocks with the verified R5 staged
// machinery. 4096 blocks; stage = 6400 floats (25.8KB) -> 6 blocks/CU
// (24 waves, 2x R5). Survivors/half = 6144+-28 (hypergeometric; 6400 = 9
// sigma; scatter clamped at SCAP for memory safety). Odd blocks count the
// first half (ballot-only, L3-warm re-read, +1 barrier) to get their output
// base -> no workspace, no cross-kernel serialization, and even/odd work
// asymmetry desyncs resident blocks. Copyout = dense coalesced scalar
// stores (probe-B-proven; base not 16B-aligned).
// Guards: LDS~26KB, VGPR 70-100, WRITE ~96-99MB. Falsifier: >=75us at >=5
// blocks/CU -> residency exonerated, plateau is structural.

#define FILLER_VAL 10.1f
constexpr int L_LEN    = 16384;
constexpr int KEEP_LEN = 12288;
constexpr int BLOCK    = 256;           // 4 waves of 64
constexpr int NW       = BLOCK / 64;
constexpr int CHUNK    = BLOCK * 4;     // 1024 elements per chunk
constexpr int HALF     = L_LEN / 2;     // 8192 elements per half-row
constexpr int NCH      = HALF / CHUNK;  // 8 chunks per half
constexpr int SCAP     = 6400;          // stage capacity (25.6 KB)

__global__ __launch_bounds__(BLOCK, 4) void compact_half_kernel(
    const float* __restrict__ x3, float* __restrict__ out)
{
    const int bid  = blockIdx.x;
    const int row  = bid >> 1;
    const int half = bid & 1;           // 0: first half, 1: second half
    const float* __restrict__ in = x3 + (size_t)row * L_LEN;
    float* __restrict__ o = out + (size_t)row * KEEP_LEN;

    const int tid  = threadIdx.x;
    const int lane = tid & 63;
    const int wid  = tid >> 6;
    const unsigned long long lt = (1ULL << lane) - 1ULL;

    __shared__ float stage[SCAP];       // 25.6 KB survivor staging
    __shared__ int wtot[NCH][NW];
    __shared__ int csum[NW];

    const float* __restrict__ seg = in + half * HALF;

    // ---- Odd blocks: issue count-half loads FIRST, then payload loads
    //      (in-order vmcnt: count consumes at vmcnt(8) while payload
    //      arrives; full MLP).  Even blocks: payload only.
    float4 u[NCH];                       // first half (count only, odd blocks)
    if (half) {
        #pragma unroll
        for (int c = 0; c < NCH; ++c)
            u[c] = *reinterpret_cast<const float4*>(in + c * CHUNK + tid * 4);
    }
    float4 v[NCH];                       // this block's compaction payload
    #pragma unroll
    for (int c = 0; c < NCH; ++c)
        v[c] = *reinterpret_cast<const float4*>(seg + c * CHUNK + tid * 4);

    // ---- Output base: 0 for even; first-half survivor count for odd.
    int base = 0;
    if (half) {
        int wcnt = 0;
        #pragma unroll
        for (int c = 0; c < NCH; ++c) {
            wcnt += __popcll(__ballot(u[c].x != FILLER_VAL))
                  + __popcll(__ballot(u[c].y != FILLER_VAL))
                  + __popcll(__ballot(u[c].z != FILLER_VAL))
                  + __popcll(__ballot(u[c].w != FILLER_VAL));
        }
        if (lane == 0) csum[wid] = wcnt;
        __syncthreads();                 // odd-only barrier (block-uniform, safe)
        base = csum[0] + csum[1] + csum[2] + csum[3];
    }

    // ---- Ballot + pack per-chunk state (R5-verified machinery, NC=8).
    int pk[NCH];
    #pragma unroll
    for (int c = 0; c < NCH; ++c) {
        const unsigned long long m0 = __ballot(v[c].x != FILLER_VAL);
        const unsigned long long m1 = __ballot(v[c].y != FILLER_VAL);
        const unsigned long long m2 = __ballot(v[c].z != FILLER_VAL);
        const unsigned long long m3 = __ballot(v[c].w != FILLER_VAL);
        const int before = __popcll(m0 & lt) + __popcll(m1 & lt)
                         + __popcll(m2 & lt) + __popcll(m3 & lt);
        const int bits = (int)((m0 >> lane) & 1ULL)
                       | ((int)((m1 >> lane) & 1ULL) << 1)
                       | ((int)((m2 >> lane) & 1ULL) << 2)
                       | ((int)((m3 >> lane) & 1ULL) << 3);
        pk[c] = bits | (before << 4);
        if (lane == 0)
            wtot[c][wid] = __popcll(m0) + __popcll(m1)
                         + __popcll(m2) + __popcll(m3);
    }
    __syncthreads();                     // wtot visible

    // ---- Prefix over (chunk, wave) + scatter values into LDS stage.
    int run = 0;
    #pragma unroll
    for (int c = 0; c < NCH; ++c) {
        int wb = run;
        #pragma unroll
        for (int w = 0; w < NW; ++w) {
            const int t = wtot[c][w];
            if (w < wid) wb += t;
            run += t;
        }
        const int bits   = pk[c] & 15;
        const int before = pk[c] >> 4;
        const int p0 = wb + before;
        const int p1 = p0 + (bits & 1);
        const int p2 = p1 + ((bits >> 1) & 1);
        const int p3 = p2 + ((bits >> 2) & 1);
        if ((bits & 1) && p0 < SCAP) stage[p0] = v[c].x;
        if ((bits & 2) && p1 < SCAP) stage[p1] = v[c].y;
        if ((bits & 4) && p2 < SCAP) stage[p2] = v[c].z;
        if ((bits & 8) && p3 < SCAP) stage[p3] = v[c].w;
    }
    __syncthreads();                     // stage complete; run = my count

    // ---- Dense coalesced copy-out (scalar; base not 16B-aligned for odd).
    const int n = (run < SCAP) ? run : SCAP;
    for (int i = tid; i < n; i += BLOCK) {
        const int gp = base + i;
        if (gp < KEEP_LEN) o[gp] = stage[i];
    }
}

extern "C" void kernel_launch(void* const* d_in, const int* in_sizes, int n_in,
                              void* d_out, int out_size, void* d_ws, size_t ws_size,
                              hipStream_t stream)
{
    // in order: x1 [B,C,4096] f32 (unused), x2 [B,C,4096] f32 (unused),
    //           x3 [B,C,L] f32, keep_len (scalar int, value 12288)
    const float* x3 = (const float*)d_in[2];
    float* out = (float*)d_out;

    const int rows = in_sizes[2] / L_LEN;  // B*C = 2048

    compact_half_kernel<<<rows * 2, BLOCK, 0, stream>>>(x3, out);
}